// Round 1
// baseline (6395.552 us; speedup 1.0000x reference)
//
#include <hip/hip_runtime.h>
#include <hip/hip_bf16.h>
#include <stddef.h>
#include <stdint.h>

#define T_STEPS 512
#define B_SZ 256
#define H_SZ 256
#define G4H 1024  // 4*H

typedef __attribute__((ext_vector_type(8))) short bf16x8;
typedef __attribute__((ext_vector_type(4))) float f32x4;

__device__ __forceinline__ unsigned short f2bf(float f) {
  union { float f; unsigned u; } v; v.f = f;
  unsigned r = v.u + 0x7fffu + ((v.u >> 16) & 1u);
  return (unsigned short)(r >> 16);
}
__device__ __forceinline__ float bf2f(unsigned short h) {
  union { unsigned u; float f; } v; v.u = ((unsigned)h) << 16; return v.f;
}
__device__ __forceinline__ float sigmoid_f(float x) {
  return 1.0f / (1.0f + __expf(-x));
}
__device__ __forceinline__ float tanh_f(float x) {
  // safe at large |x|: exp->inf gives 1-0, exp->0 gives 1-2
  return 1.0f - 2.0f / (__expf(2.0f * x) + 1.0f);
}

// ---------------- prep: fp32->bf16 weights, bias sum, state init ----------------
__global__ void prep_kernel(const float* __restrict__ h0, const float* __restrict__ c0,
                            const float* __restrict__ W_ih, const float* __restrict__ W_hh,
                            const float* __restrict__ b_ih, const float* __restrict__ b_hh,
                            unsigned short* __restrict__ Wih_bf, unsigned short* __restrict__ Whh_bf,
                            float* __restrict__ bias, unsigned short* __restrict__ h_st,
                            float* __restrict__ c_st) {
  int i = blockIdx.x * 256 + threadIdx.x;
  int stride = gridDim.x * 256;
  for (int k = i; k < G4H * H_SZ; k += stride) {
    Wih_bf[k] = f2bf(W_ih[k]);
    Whh_bf[k] = f2bf(W_hh[k]);
  }
  for (int k = i; k < B_SZ * H_SZ; k += stride) {
    h_st[k] = f2bf(h0[k]);
    c_st[k] = c0[k];
  }
  for (int k = i; k < G4H; k += stride) bias[k] = b_ih[k] + b_hh[k];
}

// ---------------- K1: xg[s,b,n] = bf16( embed[idx[t0+s,b],:] @ W_ih^T + b_ih + b_hh )
// grid: (Ci*4, 4) blocks of 256 threads. block.x -> 64-row M tile, block.y -> 256-col N group.
__global__ __launch_bounds__(256, 2) void xgate_kernel(
    const int* __restrict__ enc, const float* __restrict__ embed,
    const unsigned short* __restrict__ Wih_bf, const float* __restrict__ bias,
    unsigned short* __restrict__ xg, int t0, int Ci) {
  __shared__ unsigned short As[64][264];
  const int tid = threadIdx.x;
  const int mbase = blockIdx.x * 64;

  // stage A tile: 64 rows of embed (gather), fp32 -> bf16
  {
    int r = tid >> 2, q = tid & 3;
    int mg = mbase + r;
    int s = mg >> 8, b = mg & 255;
    int vid = enc[(t0 + s) * B_SZ + b];
    const float4* src = (const float4*)(embed + (size_t)vid * H_SZ) + q * 16;
#pragma unroll
    for (int j = 0; j < 16; ++j) {
      float4 x = src[j];
      ushort4 o;
      o.x = f2bf(x.x); o.y = f2bf(x.y); o.z = f2bf(x.z); o.w = f2bf(x.w);
      *(ushort4*)&As[r][q * 64 + j * 4] = o;
    }
  }
  __syncthreads();

  const int wave = tid >> 6, lane = tid & 63;
  const int lrow = lane & 15, quad = lane >> 4;
  const int n0 = blockIdx.y * 256 + wave * 64;

  // A fragments fully resident: 4 m-tiles x 8 k-steps
  bf16x8 af[4][8];
#pragma unroll
  for (int mt = 0; mt < 4; ++mt)
#pragma unroll
    for (int ks = 0; ks < 8; ++ks)
      af[mt][ks] = *(const bf16x8*)&As[mt * 16 + lrow][ks * 32 + quad * 8];

#pragma unroll
  for (int nt = 0; nt < 4; ++nt) {
    const int nrow = n0 + nt * 16 + lrow;  // W_ih row (gate index)
    const unsigned short* wrow = Wih_bf + (size_t)nrow * H_SZ + quad * 8;
    bf16x8 bf[8];
#pragma unroll
    for (int ks = 0; ks < 8; ++ks) bf[ks] = *(const bf16x8*)(wrow + ks * 32);
    const float bs = bias[nrow];
#pragma unroll
    for (int mt = 0; mt < 4; ++mt) {
      f32x4 a = {0.f, 0.f, 0.f, 0.f};
#pragma unroll
      for (int ks = 0; ks < 8; ++ks)
        a = __builtin_amdgcn_mfma_f32_16x16x32_bf16(af[mt][ks], bf[ks], a, 0, 0, 0);
      // store: row m = mbase + mt*16 + quad*4 + r ; col = nrow
#pragma unroll
      for (int r = 0; r < 4; ++r) {
        int m = mbase + mt * 16 + quad * 4 + r;
        xg[(size_t)m * G4H + nrow] = f2bf(a[r] + bs);
      }
    }
  }
}

// ---------------- K2: recurrent chunk. grid: 16 blocks x 256 threads, each owns 16 batches.
__global__ __launch_bounds__(256, 1) void lstm_kernel(
    const unsigned short* __restrict__ Whh_bf, const unsigned short* __restrict__ xg,
    unsigned short* __restrict__ h_st, float* __restrict__ c_st, float* __restrict__ out,
    int Ci, int is_last) {
  __shared__ unsigned short Hs[16][264];
  const int tid = threadIdx.x, wave = tid >> 6, lane = tid & 63;
  const int lrow = lane & 15, quad = lane >> 4;
  const int b0 = blockIdx.x * 16;

  // load h (bf16) into LDS
  {
    int r = tid >> 4;
    int cq = (tid & 15) * 16;
    const unsigned short* src = h_st + (size_t)(b0 + r) * H_SZ + cq;
    *(uint4*)&Hs[r][cq] = *(const uint4*)(src);
    *(uint4*)&Hs[r][cq + 8] = *(const uint4*)(src + 8);
  }
  // load c into regs; lane holds (m = quad*4+r, j = wave*64 + nt*16 + lrow)
  float creg[4][4];
#pragma unroll
  for (int nt = 0; nt < 4; ++nt)
#pragma unroll
    for (int r = 0; r < 4; ++r)
      creg[nt][r] = c_st[(size_t)(b0 + quad * 4 + r) * H_SZ + wave * 64 + nt * 16 + lrow];
  float hv[4][4];
  __syncthreads();

  const unsigned short* wbase = Whh_bf + (size_t)(wave * 64 + lrow) * H_SZ + quad * 8;

#pragma unroll 1
  for (int s = 0; s < Ci; ++s) {
    // A fragments (h tile) from LDS
    bf16x8 af[8];
#pragma unroll
    for (int ks = 0; ks < 8; ++ks)
      af[ks] = *(const bf16x8*)&Hs[lrow][ks * 32 + quad * 8];
    __syncthreads();  // all waves done reading h_{t-1} before anyone overwrites

    f32x4 acc[4][4];  // [gate][nt]
    bf16x8 bcur[8], bnxt[8];
#pragma unroll
    for (int ks = 0; ks < 8; ++ks) bcur[ks] = *(const bf16x8*)(wbase + ks * 32);
#pragma unroll
    for (int idx = 0; idx < 16; ++idx) {
      const int g = idx >> 2, nt = idx & 3;
      if (idx < 15) {
        const int g2 = (idx + 1) >> 2, nt2 = (idx + 1) & 3;
        const unsigned short* w2 = wbase + (size_t)(g2 * 256 + nt2 * 16) * H_SZ;
#pragma unroll
        for (int ks = 0; ks < 8; ++ks) bnxt[ks] = *(const bf16x8*)(w2 + ks * 32);
      }
      f32x4 a = {0.f, 0.f, 0.f, 0.f};
#pragma unroll
      for (int ks = 0; ks < 8; ++ks)
        a = __builtin_amdgcn_mfma_f32_16x16x32_bf16(af[ks], bcur[ks], a, 0, 0, 0);
      acc[g][nt] = a;
#pragma unroll
      for (int ks = 0; ks < 8; ++ks) bcur[ks] = bnxt[ks];
    }

    // elementwise LSTM update
    const unsigned short* xrow = xg + ((size_t)s * B_SZ + b0) * G4H;
#pragma unroll
    for (int nt = 0; nt < 4; ++nt) {
      const int j = wave * 64 + nt * 16 + lrow;
#pragma unroll
      for (int r = 0; r < 4; ++r) {
        const int m = quad * 4 + r;
        const size_t rb = (size_t)m * G4H + j;
        float gi = acc[0][nt][r] + bf2f(xrow[rb + 0 * H_SZ]);
        float gf = acc[1][nt][r] + bf2f(xrow[rb + 1 * H_SZ]);
        float gg = acc[2][nt][r] + bf2f(xrow[rb + 2 * H_SZ]);
        float go = acc[3][nt][r] + bf2f(xrow[rb + 3 * H_SZ]);
        gi = sigmoid_f(gi);
        gf = sigmoid_f(gf);
        gg = tanh_f(gg);
        go = sigmoid_f(go);
        float c = gf * creg[nt][r] + gi * gg;
        creg[nt][r] = c;
        float h = go * tanh_f(c);
        hv[nt][r] = h;
        Hs[m][j] = f2bf(h);
      }
    }
    __syncthreads();  // h_t visible to all waves
  }

  // persist state (and final output)
#pragma unroll
  for (int nt = 0; nt < 4; ++nt)
#pragma unroll
    for (int r = 0; r < 4; ++r) {
      const int m = quad * 4 + r, j = wave * 64 + nt * 16 + lrow;
      const size_t gidx = (size_t)(b0 + m) * H_SZ + j;
      h_st[gidx] = f2bf(hv[nt][r]);
      c_st[gidx] = creg[nt][r];
      if (is_last) {
        out[gidx] = hv[nt][r];                    // h
        out[(size_t)B_SZ * H_SZ + gidx] = creg[nt][r];  // c
      }
    }
}

extern "C" void kernel_launch(void* const* d_in, const int* in_sizes, int n_in,
                              void* d_out, int out_size, void* d_ws, size_t ws_size,
                              hipStream_t stream) {
  const int* enc = (const int*)d_in[0];
  const float* h0 = (const float*)d_in[1];
  const float* c0 = (const float*)d_in[2];
  const float* embed = (const float*)d_in[3];
  const float* W_ih = (const float*)d_in[4];
  const float* W_hh = (const float*)d_in[5];
  const float* b_ih = (const float*)d_in[6];
  const float* b_hh = (const float*)d_in[7];
  float* out = (float*)d_out;

  char* ws = (char*)d_ws;
  unsigned short* Wih_bf = (unsigned short*)(ws);                  // 512 KB
  unsigned short* Whh_bf = (unsigned short*)(ws + (512 << 10));    // 512 KB
  float* bias = (float*)(ws + (1024 << 10));                       // 4 KB
  unsigned short* h_st = (unsigned short*)(ws + (1028 << 10));     // 128 KB
  float* c_st = (float*)(ws + (1156 << 10));                       // 256 KB
  const size_t fixed = (size_t)(1412) << 10;
  unsigned short* xg = (unsigned short*)(ws + fixed);

  const size_t per_step = (size_t)B_SZ * G4H * 2;  // 512 KB per timestep (bf16)
  int C = 1;
  if (ws_size > fixed + per_step) {
    size_t c = (ws_size - fixed) / per_step;
    C = (c > T_STEPS) ? T_STEPS : (int)c;
  }

  prep_kernel<<<dim3(256), dim3(256), 0, stream>>>(h0, c0, W_ih, W_hh, b_ih, b_hh,
                                                   Wih_bf, Whh_bf, bias, h_st, c_st);
  for (int t0 = 0; t0 < T_STEPS; t0 += C) {
    int Ci = (T_STEPS - t0 < C) ? (T_STEPS - t0) : C;
    xgate_kernel<<<dim3(Ci * 4, 4), dim3(256), 0, stream>>>(enc, embed, Wih_bf, bias,
                                                            xg, t0, Ci);
    int is_last = (t0 + Ci) >= T_STEPS;
    lstm_kernel<<<dim3(16), dim3(256), 0, stream>>>(Whh_bf, xg, h_st, c_st, out,
                                                    Ci, is_last);
  }
}